// Round 7
// baseline (57.134 us; speedup 1.0000x reference)
//
#include <hip/hip_runtime.h>
#include <stdint.h>

// ---------------------------------------------------------------------------
// AdditiveAttention (Bahdanau) + gumbel-softmax(tau=0.01), channel 0.
//
// out[b,i,j] = (mask==1) ? 1.0
//            : sigmoid( (d + g0 - g1) * 100 ),  d = sum_h tanh(q+k)*(w0-w1)
//
// g = jax.random.gumbel(key(42)) bit-exact (threefry-2x32, partitionable,
// o0^o1) — verified passing R3-R6.
//
// R7: attn latency fix. R6 was LDS-latency-bound (ILP change was neutral,
// VALUBusy 58%): ds_read ~120cy latency exposed at 4 waves/SIMD. Now:
//  - explicit register double-buffer: prefetch h4+1 fragments before
//    computing h4 (compute ~500cy >> 120cy latency -> hidden at any occ)
//  - 8 outputs/thread (4i x 2j): 6 ds_read per wave-h4 feed 512 site-groups
//    (LDS pipe 12.8 -> 7.7 us/CU)
// tanh(q+k) = (tq+tk)/(1+tq*tk), tq/tk precomputed by proj (R6, verified).
// ---------------------------------------------------------------------------

#define BB 4
#define LLEN 512
#define DD 256
#define HH 128

#define LOG2E_100 144.26950408889634f   // 100*log2(e)

__device__ __forceinline__ uint32_t rotl32(uint32_t v, int r) {
  return (v << r) | (v >> (32 - r));
}

// Threefry-2x32, key = (0, 42)
__device__ __forceinline__ void tf2x32(uint32_t x0, uint32_t x1,
                                       uint32_t& o0, uint32_t& o1) {
  const uint32_t k0 = 0u;
  const uint32_t k1 = 42u;
  const uint32_t k2 = 0x1BD11BDAu ^ k0 ^ k1;

  x0 += k0; x1 += k1;
#define TFR(r) { x0 += x1; x1 = rotl32(x1, (r)); x1 ^= x0; }
  TFR(13) TFR(15) TFR(26) TFR(6)
  x0 += k1; x1 += k2 + 1u;
  TFR(17) TFR(29) TFR(16) TFR(24)
  x0 += k2; x1 += k0 + 2u;
  TFR(13) TFR(15) TFR(26) TFR(6)
  x0 += k0; x1 += k1 + 3u;
  TFR(17) TFR(29) TFR(16) TFR(24)
  x0 += k1; x1 += k2 + 4u;
  TFR(13) TFR(15) TFR(26) TFR(6)
  x0 += k2; x1 += k0 + 5u;
#undef TFR
  o0 = x0; o1 = x1;
}

// jax partitionable random_bits: counter u64 = flat -> block (0, flat), o0^o1
__device__ __forceinline__ float jax_gumbel(uint32_t flat) {
  uint32_t o0, o1;
  tf2x32(0u, flat, o0, o1);
  const uint32_t bits = o0 ^ o1;
  const float f = __uint_as_float((bits >> 9) | 0x3F800000u) - 1.0f;
  const float u = fmaxf(f, 1.17549435e-38f);
  const float L = -__logf(u);
  return -__logf(L);
}

// ---------------------------------------------------------------------------
// Kernel A: projections -> tq = tanh(q.Wq^T), tk = tanh(k.Wk^T).
// Each block: rows [rb, rb+8) of BOTH Q and K (shares the W pass).
// ---------------------------------------------------------------------------
__global__ __launch_bounds__(256) void proj_kernel(
    const float* __restrict__ queries, const float* __restrict__ keys,
    const float* __restrict__ Wq, const float* __restrict__ Wk,
    float* __restrict__ Qp, float* __restrict__ Kp) {
  const int rb = blockIdx.x * 8;

  __shared__ float rows[2][8][DD];
  const int side_sz = 8 * DD / 4;
  for (int t = threadIdx.x; t < 2 * side_sz; t += 256) {
    const int s = t / side_sz;
    const int o = t - s * side_sz;
    const float4 v = reinterpret_cast<const float4*>(s ? keys : queries)
                         [(size_t)rb * (DD / 4) + o];
    reinterpret_cast<float4*>(&rows[s][0][0])[o] = v;
  }
  __syncthreads();

  const int h = threadIdx.x & 127;
  const int side = threadIdx.x >> 7;
  const float* __restrict__ W = side ? Wk : Wq;
  float* __restrict__ outp = side ? Kp : Qp;

  const float4* W4 = reinterpret_cast<const float4*>(W + (size_t)h * DD);
  float a[8] = {0.f, 0.f, 0.f, 0.f, 0.f, 0.f, 0.f, 0.f};
  for (int d4 = 0; d4 < DD / 4; ++d4) {
    const float4 w = W4[d4];
    const int d = d4 * 4;
    #pragma unroll
    for (int rr = 0; rr < 8; ++rr) {
      const float* rp = &rows[side][rr][d];   // wave-uniform: LDS broadcast
      a[rr] = fmaf(w.x, rp[0], fmaf(w.y, rp[1], fmaf(w.z, rp[2], fmaf(w.w, rp[3], a[rr]))));
    }
  }
  #pragma unroll
  for (int rr = 0; rr < 8; ++rr)
    outp[(size_t)(rb + rr) * HH + h] = tanhf(a[rr]);
}

// ---------------------------------------------------------------------------
// Kernel B: 32i x 64j tile per block (grid 16x8x4), 256 threads,
// 8 outputs/thread (4i x 2j). Register-double-buffered LDS reads.
// ---------------------------------------------------------------------------

// one site: acc += wd * (tq+tk)/(1+tq*tk)
#define CMP1(accv, qx, kx, wdx) {                  \
    const float s_  = (qx) + (kx);                 \
    const float dn_ = fmaf((qx), (kx), 1.0f);      \
    const float rc_ = __builtin_amdgcn_rcpf(dn_);  \
    (accv) = fmaf((wdx), s_ * rc_, (accv)); }

#define CMP4(af4, qv, kv, wd)          \
    CMP1((af4).x, (qv).x, (kv).x, (wd).x) \
    CMP1((af4).y, (qv).y, (kv).y, (wd).y) \
    CMP1((af4).z, (qv).z, (kv).z, (wd).z) \
    CMP1((af4).w, (qv).w, (kv).w, (wd).w)

#define COMPUTE(k0, k1, q0, q1, q2, q3, wd)          \
    CMP4(acc[0][0], q0, k0, wd) CMP4(acc[0][1], q0, k1, wd) \
    CMP4(acc[1][0], q1, k0, wd) CMP4(acc[1][1], q1, k1, wd) \
    CMP4(acc[2][0], q2, k0, wd) CMP4(acc[2][1], q2, k1, wd) \
    CMP4(acc[3][0], q3, k0, wd) CMP4(acc[3][1], q3, k1, wd)

__global__ __launch_bounds__(256, 4) void attn_kernel(
    const float* __restrict__ Qp, const float* __restrict__ Kp,
    const int* __restrict__ mask, const float* __restrict__ Wv,
    float* __restrict__ out) {
  __shared__ float4 QL[32][33];   // tq tile (16.9 KB)
  __shared__ float4 KL[64][33];   // tk tile (33.8 KB)
  __shared__ float4 wdL[32];      // Wv[0][h]-Wv[1][h]

  const int bi = blockIdx.x, bj = blockIdx.y, b = blockIdx.z;
  const int i0 = bi * 32, j0 = bj * 64;

  const float4* Q4 = reinterpret_cast<const float4*>(Qp) + ((size_t)b * LLEN + i0) * (HH / 4);
  const float4* K4 = reinterpret_cast<const float4*>(Kp) + ((size_t)b * LLEN + j0) * (HH / 4);
  for (int t = threadIdx.x; t < 1024 + 2048; t += 256) {
    if (t < 1024) {
      QL[t >> 5][t & 31] = Q4[t];
    } else {
      const int u = t - 1024;
      KL[u >> 5][u & 31] = K4[u];
    }
  }
  if (threadIdx.x < 32) {
    const float4 w0 = reinterpret_cast<const float4*>(Wv)[threadIdx.x];
    const float4 w1 = reinterpret_cast<const float4*>(Wv)[32 + threadIdx.x];
    float4 wd; wd.x = w0.x - w1.x; wd.y = w0.y - w1.y;
    wd.z = w0.z - w1.z; wd.w = w0.w - w1.w;
    wdL[threadIdx.x] = wd;
  }
  __syncthreads();

  const int jj = threadIdx.x & 31;   // j in [0,32): handles j0+jj, j0+jj+32
  const int ib = threadIdx.x >> 5;   // i rows: ib, ib+8, ib+16, ib+24

  // mask prefetch (hides cold-HBM latency under the main loop)
  const uint32_t row_i = (uint32_t)b * LLEN + i0 + ib;
  int mreg[4][2];
  #pragma unroll
  for (int r = 0; r < 4; ++r)
    #pragma unroll
    for (int c = 0; c < 2; ++c)
      mreg[r][c] = mask[(row_i + 8u * r) * LLEN + j0 + jj + 32 * c];

  float4 acc[4][2];
  #pragma unroll
  for (int r = 0; r < 4; ++r)
    #pragma unroll
    for (int c = 0; c < 2; ++c) {
      acc[r][c].x = 0.f; acc[r][c].y = 0.f;
      acc[r][c].z = 0.f; acc[r][c].w = 0.f;
    }

  // register pipeline: A-set holds h4, B-set holds h4+1
  float4 ka0 = KL[jj][0],      ka1 = KL[jj + 32][0];
  float4 qa0 = QL[ib][0],      qa1 = QL[ib + 8][0];
  float4 qa2 = QL[ib + 16][0], qa3 = QL[ib + 24][0];

  for (int h4 = 0; h4 < HH / 4; h4 += 2) {
    // prefetch B (h4+1) before consuming A
    const float4 kb0 = KL[jj][h4 + 1],      kb1 = KL[jj + 32][h4 + 1];
    const float4 qb0 = QL[ib][h4 + 1],      qb1 = QL[ib + 8][h4 + 1];
    const float4 qb2 = QL[ib + 16][h4 + 1], qb3 = QL[ib + 24][h4 + 1];
    float4 wd = wdL[h4];
    COMPUTE(ka0, ka1, qa0, qa1, qa2, qa3, wd);

    // prefetch A (h4+2; &31 wraps harmlessly on the last iter)
    const int nx = (h4 + 2) & 31;
    ka0 = KL[jj][nx];      ka1 = KL[jj + 32][nx];
    qa0 = QL[ib][nx];      qa1 = QL[ib + 8][nx];
    qa2 = QL[ib + 16][nx]; qa3 = QL[ib + 24][nx];
    wd = wdL[h4 + 1];
    COMPUTE(kb0, kb1, qb0, qb1, qb2, qb3, wd);
  }

  #pragma unroll
  for (int r = 0; r < 4; ++r) {
    #pragma unroll
    for (int c = 0; c < 2; ++c) {
      const uint32_t idx = (row_i + 8u * r) * LLEN + j0 + jj + 32 * c;
      float o = 1.0f;                  // mask==1: channel 1 at -1e6 -> exactly 1
      if (mreg[r][c] >= 2) {
        const float4 a = acc[r][c];
        const float d = (a.x + a.y) + (a.z + a.w);
        const float g0 = jax_gumbel(idx * 2u);
        const float g1 = jax_gumbel(idx * 2u + 1u);
        const float t = (d + g0 - g1) * LOG2E_100;
        o = __builtin_amdgcn_rcpf(1.0f + __builtin_amdgcn_exp2f(-t));
      }
      out[idx] = o;
    }
  }
}

extern "C" void kernel_launch(void* const* d_in, const int* in_sizes, int n_in,
                              void* d_out, int out_size, void* d_ws, size_t ws_size,
                              hipStream_t stream) {
  const float* queries = (const float*)d_in[0];
  const float* keys    = (const float*)d_in[1];
  const int*   mask    = (const int*)d_in[2];
  const float* Wq      = (const float*)d_in[3];
  const float* Wk      = (const float*)d_in[4];
  const float* Wv      = (const float*)d_in[5];
  float* out = (float*)d_out;

  float* Qp = (float*)d_ws;                 // tq [2048][128]
  float* Kp = Qp + (size_t)BB * LLEN * HH;  // tk [2048][128]

  proj_kernel<<<dim3(BB * LLEN / 8), dim3(256), 0, stream>>>(
      queries, keys, Wq, Wk, Qp, Kp);
  attn_kernel<<<dim3(LLEN / 32, LLEN / 64, BB), dim3(256), 0, stream>>>(
      Qp, Kp, mask, Wv, out);
}

// Round 8
// 48.410 us; speedup vs baseline: 1.1802x; 1.1802x over previous
//
#include <hip/hip_runtime.h>
#include <stdint.h>

// ---------------------------------------------------------------------------
// AdditiveAttention (Bahdanau) + gumbel-softmax(tau=0.01), channel 0.
//
// out[b,i,j] = (mask==1) ? 1.0
//            : sigmoid( (d + g0 - g1) * 100 ),  d = sum_h tanh(q+k)*(w0-w1)
//
// g = jax.random.gumbel(key(42)) bit-exact (threefry-2x32, partitionable,
// o0^o1) — verified passing R3-R7.
//
// R8: exp-product inner loop. Proj stores EQ=exp2(c*q), EK=exp2(c*k),
// c=2*log2e. Then e^{2(q+k)} = EQ*EK and tanh = 1 - 2*rcp(EQ*EK+1):
//   site = fma(dn), v_rcp, fma(acc)  -> 2 full-rate + 1 trans (R7 was 5 inst)
// Channel fold (R5-verified): d = Swd - 2*sum_h wd_h*rc_h.
// Proj: 4 rows x 1 side per block (grid 1024, was 256) — R7 proj was
// ~14us at 1 block/CU with a serialized uniform-read chain.
// ---------------------------------------------------------------------------

#define BB 4
#define LLEN 512
#define DD 256
#define HH 128

#define TWO_LOG2E 2.8853900817779268f   // 2*log2(e)
#define LOG2E_100 144.26950408889634f   // 100*log2(e)

__device__ __forceinline__ uint32_t rotl32(uint32_t v, int r) {
  return (v << r) | (v >> (32 - r));
}

// Threefry-2x32, key = (0, 42)
__device__ __forceinline__ void tf2x32(uint32_t x0, uint32_t x1,
                                       uint32_t& o0, uint32_t& o1) {
  const uint32_t k0 = 0u;
  const uint32_t k1 = 42u;
  const uint32_t k2 = 0x1BD11BDAu ^ k0 ^ k1;

  x0 += k0; x1 += k1;
#define TFR(r) { x0 += x1; x1 = rotl32(x1, (r)); x1 ^= x0; }
  TFR(13) TFR(15) TFR(26) TFR(6)
  x0 += k1; x1 += k2 + 1u;
  TFR(17) TFR(29) TFR(16) TFR(24)
  x0 += k2; x1 += k0 + 2u;
  TFR(13) TFR(15) TFR(26) TFR(6)
  x0 += k0; x1 += k1 + 3u;
  TFR(17) TFR(29) TFR(16) TFR(24)
  x0 += k1; x1 += k2 + 4u;
  TFR(13) TFR(15) TFR(26) TFR(6)
  x0 += k2; x1 += k0 + 5u;
#undef TFR
  o0 = x0; o1 = x1;
}

// jax partitionable random_bits: counter u64 = flat -> block (0, flat), o0^o1
__device__ __forceinline__ float jax_gumbel(uint32_t flat) {
  uint32_t o0, o1;
  tf2x32(0u, flat, o0, o1);
  const uint32_t bits = o0 ^ o1;
  const float f = __uint_as_float((bits >> 9) | 0x3F800000u) - 1.0f;
  const float u = fmaxf(f, 1.17549435e-38f);
  const float L = -__logf(u);
  return -__logf(L);
}

// ---------------------------------------------------------------------------
// Kernel A: projections -> EQ = exp2(c * q.Wq^T), EK = exp2(c * k.Wk^T).
// Grid 1024: blocks 0..511 = Q (4 rows each), 512..1023 = K. 128 threads.
// ---------------------------------------------------------------------------
__global__ __launch_bounds__(128) void proj_kernel(
    const float* __restrict__ queries, const float* __restrict__ keys,
    const float* __restrict__ Wq, const float* __restrict__ Wk,
    float* __restrict__ EQ, float* __restrict__ EK) {
  const int blk = blockIdx.x;
  const bool isK = blk >= 512;
  const int rb = (isK ? blk - 512 : blk) * 4;   // rows rb..rb+3 (of 2048)
  const float* __restrict__ in = isK ? keys : queries;
  const float* __restrict__ W  = isK ? Wk : Wq;
  float* __restrict__ outp     = isK ? EK : EQ;

  __shared__ float rows[4][DD];
  const float4* in4 = reinterpret_cast<const float4*>(in + (size_t)rb * DD);
  float4* rows4 = reinterpret_cast<float4*>(&rows[0][0]);
  #pragma unroll
  for (int t = threadIdx.x; t < 4 * DD / 4; t += 128) rows4[t] = in4[t];
  __syncthreads();

  const int h = threadIdx.x;
  const float4* W4 = reinterpret_cast<const float4*>(W + (size_t)h * DD);
  float a0 = 0.f, a1 = 0.f, a2 = 0.f, a3 = 0.f;
  #pragma unroll 8
  for (int d4 = 0; d4 < DD / 4; ++d4) {
    const float4 w = W4[d4];
    const int d = d4 * 4;
    a0 = fmaf(w.x, rows[0][d], fmaf(w.y, rows[0][d+1], fmaf(w.z, rows[0][d+2], fmaf(w.w, rows[0][d+3], a0))));
    a1 = fmaf(w.x, rows[1][d], fmaf(w.y, rows[1][d+1], fmaf(w.z, rows[1][d+2], fmaf(w.w, rows[1][d+3], a1))));
    a2 = fmaf(w.x, rows[2][d], fmaf(w.y, rows[2][d+1], fmaf(w.z, rows[2][d+2], fmaf(w.w, rows[2][d+3], a2))));
    a3 = fmaf(w.x, rows[3][d], fmaf(w.y, rows[3][d+1], fmaf(w.z, rows[3][d+2], fmaf(w.w, rows[3][d+3], a3))));
  }
  float* orow = outp + (size_t)rb * HH + h;
  orow[0 * HH] = __builtin_amdgcn_exp2f(a0 * TWO_LOG2E);
  orow[1 * HH] = __builtin_amdgcn_exp2f(a1 * TWO_LOG2E);
  orow[2 * HH] = __builtin_amdgcn_exp2f(a2 * TWO_LOG2E);
  orow[3 * HH] = __builtin_amdgcn_exp2f(a3 * TWO_LOG2E);
}

// ---------------------------------------------------------------------------
// Kernel B: 32i x 64j tile per block (grid 16x8x4), 256 threads,
// 8 outputs/thread (4i x 2j). site = fma, rcp, fma.
// ---------------------------------------------------------------------------

// acc += wd * rcp(EQ*EK + 1)
#define CMP1(accv, qx, kx, wdx) {                  \
    const float dn_ = fmaf((qx), (kx), 1.0f);      \
    const float rc_ = __builtin_amdgcn_rcpf(dn_);  \
    (accv) = fmaf((wdx), rc_, (accv)); }

#define CMP4(af4, qv, kv, wd)          \
    CMP1((af4).x, (qv).x, (kv).x, (wd).x) \
    CMP1((af4).y, (qv).y, (kv).y, (wd).y) \
    CMP1((af4).z, (qv).z, (kv).z, (wd).z) \
    CMP1((af4).w, (qv).w, (kv).w, (wd).w)

#define COMPUTE(k0, k1, q0, q1, q2, q3, wd)          \
    CMP4(acc[0][0], q0, k0, wd) CMP4(acc[0][1], q0, k1, wd) \
    CMP4(acc[1][0], q1, k0, wd) CMP4(acc[1][1], q1, k1, wd) \
    CMP4(acc[2][0], q2, k0, wd) CMP4(acc[2][1], q2, k1, wd) \
    CMP4(acc[3][0], q3, k0, wd) CMP4(acc[3][1], q3, k1, wd)

__global__ __launch_bounds__(256, 4) void attn_kernel(
    const float* __restrict__ EQ, const float* __restrict__ EK,
    const int* __restrict__ mask, const float* __restrict__ Wv,
    float* __restrict__ out) {
  __shared__ float4 QL[32][33];   // EQ tile (16.9 KB)
  __shared__ float4 KL[64][33];   // EK tile (33.8 KB)
  __shared__ float4 wdL[32];      // Wv[0][h]-Wv[1][h]

  const int bi = blockIdx.x, bj = blockIdx.y, b = blockIdx.z;
  const int i0 = bi * 32, j0 = bj * 64;

  const float4* Q4 = reinterpret_cast<const float4*>(EQ) + ((size_t)b * LLEN + i0) * (HH / 4);
  const float4* K4 = reinterpret_cast<const float4*>(EK) + ((size_t)b * LLEN + j0) * (HH / 4);
  for (int t = threadIdx.x; t < 1024 + 2048; t += 256) {
    if (t < 1024) {
      QL[t >> 5][t & 31] = Q4[t];
    } else {
      const int u = t - 1024;
      KL[u >> 5][u & 31] = K4[u];
    }
  }
  if (threadIdx.x < 32) {
    const float4 w0 = reinterpret_cast<const float4*>(Wv)[threadIdx.x];
    const float4 w1 = reinterpret_cast<const float4*>(Wv)[32 + threadIdx.x];
    float4 wd; wd.x = w0.x - w1.x; wd.y = w0.y - w1.y;
    wd.z = w0.z - w1.z; wd.w = w0.w - w1.w;
    wdL[threadIdx.x] = wd;
  }
  __syncthreads();

  const int jj = threadIdx.x & 31;   // j in [0,32): handles j0+jj, j0+jj+32
  const int ib = threadIdx.x >> 5;   // i rows: ib, ib+8, ib+16, ib+24

  // mask prefetch (hides cold-HBM latency under the main loop)
  const uint32_t row_i = (uint32_t)b * LLEN + i0 + ib;
  int mreg[4][2];
  #pragma unroll
  for (int r = 0; r < 4; ++r)
    #pragma unroll
    for (int c = 0; c < 2; ++c)
      mreg[r][c] = mask[(row_i + 8u * r) * LLEN + j0 + jj + 32 * c];

  // Swd = sum_h wd_h (broadcast reads, outside the hot loop)
  float Swd = 0.f;
  #pragma unroll
  for (int t = 0; t < 32; ++t) {
    const float4 wd = wdL[t];
    Swd += (wd.x + wd.y) + (wd.z + wd.w);
  }

  float4 acc[4][2];
  #pragma unroll
  for (int r = 0; r < 4; ++r)
    #pragma unroll
    for (int c = 0; c < 2; ++c) {
      acc[r][c].x = 0.f; acc[r][c].y = 0.f;
      acc[r][c].z = 0.f; acc[r][c].w = 0.f;
    }

  // register pipeline: A-set holds h4, B-set holds h4+1
  float4 ka0 = KL[jj][0],      ka1 = KL[jj + 32][0];
  float4 qa0 = QL[ib][0],      qa1 = QL[ib + 8][0];
  float4 qa2 = QL[ib + 16][0], qa3 = QL[ib + 24][0];

  for (int h4 = 0; h4 < HH / 4; h4 += 2) {
    const float4 kb0 = KL[jj][h4 + 1],      kb1 = KL[jj + 32][h4 + 1];
    const float4 qb0 = QL[ib][h4 + 1],      qb1 = QL[ib + 8][h4 + 1];
    const float4 qb2 = QL[ib + 16][h4 + 1], qb3 = QL[ib + 24][h4 + 1];
    float4 wd = wdL[h4];
    COMPUTE(ka0, ka1, qa0, qa1, qa2, qa3, wd);

    const int nx = (h4 + 2) & 31;
    ka0 = KL[jj][nx];      ka1 = KL[jj + 32][nx];
    qa0 = QL[ib][nx];      qa1 = QL[ib + 8][nx];
    qa2 = QL[ib + 16][nx]; qa3 = QL[ib + 24][nx];
    wd = wdL[h4 + 1];
    COMPUTE(kb0, kb1, qb0, qb1, qb2, qb3, wd);
  }

  #pragma unroll
  for (int r = 0; r < 4; ++r) {
    #pragma unroll
    for (int c = 0; c < 2; ++c) {
      const uint32_t idx = (row_i + 8u * r) * LLEN + j0 + jj + 32 * c;
      float o = 1.0f;                  // mask==1: channel 1 at -1e6 -> exactly 1
      if (mreg[r][c] >= 2) {
        const float4 a = acc[r][c];
        const float A = (a.x + a.y) + (a.z + a.w);
        const float d = fmaf(-2.0f, A, Swd);      // Swd - 2*sum wd*rc
        const float g0 = jax_gumbel(idx * 2u);
        const float g1 = jax_gumbel(idx * 2u + 1u);
        const float t = (d + g0 - g1) * LOG2E_100;
        o = __builtin_amdgcn_rcpf(1.0f + __builtin_amdgcn_exp2f(-t));
      }
      out[idx] = o;
    }
  }
}

extern "C" void kernel_launch(void* const* d_in, const int* in_sizes, int n_in,
                              void* d_out, int out_size, void* d_ws, size_t ws_size,
                              hipStream_t stream) {
  const float* queries = (const float*)d_in[0];
  const float* keys    = (const float*)d_in[1];
  const int*   mask    = (const int*)d_in[2];
  const float* Wq      = (const float*)d_in[3];
  const float* Wk      = (const float*)d_in[4];
  const float* Wv      = (const float*)d_in[5];
  float* out = (float*)d_out;

  float* EQ = (float*)d_ws;                 // [2048][128]
  float* EK = EQ + (size_t)BB * LLEN * HH;  // [2048][128]

  proj_kernel<<<dim3(1024), dim3(128), 0, stream>>>(
      queries, keys, Wq, Wk, EQ, EK);
  attn_kernel<<<dim3(LLEN / 32, LLEN / 64, BB), dim3(256), 0, stream>>>(
      EQ, EK, mask, Wv, out);
}

// Round 9
// 46.698 us; speedup vs baseline: 1.2235x; 1.0367x over previous
//
#include <hip/hip_runtime.h>
#include <stdint.h>

// ---------------------------------------------------------------------------
// AdditiveAttention (Bahdanau) + gumbel-softmax(tau=0.01), channel 0.
//
// out[b,i,j] = (mask==1) ? 1.0
//            : sigmoid( (d + g0 - g1) * 100 ),  d = sum_h tanh(q+k)*(w0-w1)
//
// g = jax.random.gumbel(key(42)) bit-exact (threefry-2x32, partitionable,
// o0^o1) — verified passing R3-R8.
//
// R9: TRANS-PIPE diet. Cross-round model fit: v_rcp/v_exp wave64 ~16
// SIMD-busy cy (8x full-rate) — explains VALUBusy in R3/R5/R6/R7/R8.
//  - shared-rcp 4-group: sum_{h4 chunk} wd_h/(1+x_h) = num/den with one
//    rcp per float4 chunk (was 4): 14 full + 1 trans vs 8 full + 4 trans.
//    x_h = EQ*EK = e^{2(q+k)}; den = prod(1+x) < e^55, overflow-safe.
//  - 16i x 64j tile, grid 1024 (was 512): 2 -> 3-4 blocks/CU resident.
//  - epilogue: g0-g1 = ln(l1/l0), l=log2(u): 4 logs -> 3.
// ---------------------------------------------------------------------------

#define BB 4
#define LLEN 512
#define DD 256
#define HH 128

#define TWO_LOG2E 2.8853900817779268f   // 2*log2(e)
#define LOG2E_100 144.26950408889634f   // 100*log2(e)

__device__ __forceinline__ uint32_t rotl32(uint32_t v, int r) {
  return (v << r) | (v >> (32 - r));
}

// Threefry-2x32, key = (0, 42)
__device__ __forceinline__ void tf2x32(uint32_t x0, uint32_t x1,
                                       uint32_t& o0, uint32_t& o1) {
  const uint32_t k0 = 0u;
  const uint32_t k1 = 42u;
  const uint32_t k2 = 0x1BD11BDAu ^ k0 ^ k1;

  x0 += k0; x1 += k1;
#define TFR(r) { x0 += x1; x1 = rotl32(x1, (r)); x1 ^= x0; }
  TFR(13) TFR(15) TFR(26) TFR(6)
  x0 += k1; x1 += k2 + 1u;
  TFR(17) TFR(29) TFR(16) TFR(24)
  x0 += k2; x1 += k0 + 2u;
  TFR(13) TFR(15) TFR(26) TFR(6)
  x0 += k0; x1 += k1 + 3u;
  TFR(17) TFR(29) TFR(16) TFR(24)
  x0 += k1; x1 += k2 + 4u;
  TFR(13) TFR(15) TFR(26) TFR(6)
  x0 += k2; x1 += k0 + 5u;
#undef TFR
  o0 = x0; o1 = x1;
}

// u in (0,1) from jax partitionable random_bits (counter (0,flat), o0^o1)
__device__ __forceinline__ float jax_u01(uint32_t flat) {
  uint32_t o0, o1;
  tf2x32(0u, flat, o0, o1);
  const uint32_t bits = o0 ^ o1;
  const float f = __uint_as_float((bits >> 9) | 0x3F800000u) - 1.0f;
  return fmaxf(f, 1.17549435e-38f);
}

// ---------------------------------------------------------------------------
// Kernel A: projections -> EQ = exp2(c * q.Wq^T), EK = exp2(c * k.Wk^T).
// Grid 1024: blocks 0..511 = Q (4 rows each), 512..1023 = K. 128 threads.
// ---------------------------------------------------------------------------
__global__ __launch_bounds__(128) void proj_kernel(
    const float* __restrict__ queries, const float* __restrict__ keys,
    const float* __restrict__ Wq, const float* __restrict__ Wk,
    float* __restrict__ EQ, float* __restrict__ EK) {
  const int blk = blockIdx.x;
  const bool isK = blk >= 512;
  const int rb = (isK ? blk - 512 : blk) * 4;   // rows rb..rb+3 (of 2048)
  const float* __restrict__ in = isK ? keys : queries;
  const float* __restrict__ W  = isK ? Wk : Wq;
  float* __restrict__ outp     = isK ? EK : EQ;

  __shared__ float rows[4][DD];
  const float4* in4 = reinterpret_cast<const float4*>(in + (size_t)rb * DD);
  float4* rows4 = reinterpret_cast<float4*>(&rows[0][0]);
  #pragma unroll
  for (int t = threadIdx.x; t < 4 * DD / 4; t += 128) rows4[t] = in4[t];
  __syncthreads();

  const int h = threadIdx.x;
  const float4* W4 = reinterpret_cast<const float4*>(W + (size_t)h * DD);
  float a0 = 0.f, a1 = 0.f, a2 = 0.f, a3 = 0.f;
  #pragma unroll 8
  for (int d4 = 0; d4 < DD / 4; ++d4) {
    const float4 w = W4[d4];
    const int d = d4 * 4;
    a0 = fmaf(w.x, rows[0][d], fmaf(w.y, rows[0][d+1], fmaf(w.z, rows[0][d+2], fmaf(w.w, rows[0][d+3], a0))));
    a1 = fmaf(w.x, rows[1][d], fmaf(w.y, rows[1][d+1], fmaf(w.z, rows[1][d+2], fmaf(w.w, rows[1][d+3], a1))));
    a2 = fmaf(w.x, rows[2][d], fmaf(w.y, rows[2][d+1], fmaf(w.z, rows[2][d+2], fmaf(w.w, rows[2][d+3], a2))));
    a3 = fmaf(w.x, rows[3][d], fmaf(w.y, rows[3][d+1], fmaf(w.z, rows[3][d+2], fmaf(w.w, rows[3][d+3], a3))));
  }
  float* orow = outp + (size_t)rb * HH + h;
  orow[0 * HH] = __builtin_amdgcn_exp2f(a0 * TWO_LOG2E);
  orow[1 * HH] = __builtin_amdgcn_exp2f(a1 * TWO_LOG2E);
  orow[2 * HH] = __builtin_amdgcn_exp2f(a2 * TWO_LOG2E);
  orow[3 * HH] = __builtin_amdgcn_exp2f(a3 * TWO_LOG2E);
}

// ---------------------------------------------------------------------------
// Kernel B: 16i x 64j tile per block (grid 32x8x4 = 1024), 256 threads,
// 4 outputs/thread (2i x 2j). Shared-rcp 4-group inner loop:
//   sum_{h in chunk4} wd_h/(1+x_h) = num/den, one v_rcp per chunk.
// ---------------------------------------------------------------------------

#define GRP(accv, qv, kv, wd) {                                       \
    float4 A_;                                                        \
    A_.x = fmaf((qv).x, (kv).x, 1.0f);                                \
    A_.y = fmaf((qv).y, (kv).y, 1.0f);                                \
    A_.z = fmaf((qv).z, (kv).z, 1.0f);                                \
    A_.w = fmaf((qv).w, (kv).w, 1.0f);                                \
    const float p01_ = A_.x * A_.y;                                   \
    const float p23_ = A_.z * A_.w;                                   \
    const float n01_ = fmaf((wd).x, A_.y, (wd).y * A_.x);             \
    const float n23_ = fmaf((wd).z, A_.w, (wd).w * A_.z);             \
    const float num_ = fmaf(n01_, p23_, n23_ * p01_);                 \
    const float rc_  = __builtin_amdgcn_rcpf(p01_ * p23_);            \
    (accv) = fmaf(num_, rc_, (accv)); }

__global__ __launch_bounds__(256) void attn_kernel(
    const float* __restrict__ EQ, const float* __restrict__ EK,
    const int* __restrict__ mask, const float* __restrict__ Wv,
    float* __restrict__ out) {
  __shared__ float4 QL[16][33];   // EQ tile (8.4 KB)
  __shared__ float4 KL[64][33];   // EK tile (33.8 KB)
  __shared__ float4 wdL[32];      // Wv[0][h]-Wv[1][h]

  const int bi = blockIdx.x, bj = blockIdx.y, b = blockIdx.z;
  const int i0 = bi * 16, j0 = bj * 64;

  const float4* Q4 = reinterpret_cast<const float4*>(EQ) + ((size_t)b * LLEN + i0) * (HH / 4);
  const float4* K4 = reinterpret_cast<const float4*>(EK) + ((size_t)b * LLEN + j0) * (HH / 4);
  for (int t = threadIdx.x; t < 512 + 2048; t += 256) {
    if (t < 512) {
      QL[t >> 5][t & 31] = Q4[t];
    } else {
      const int u = t - 512;
      KL[u >> 5][u & 31] = K4[u];
    }
  }
  if (threadIdx.x < 32) {
    const float4 w0 = reinterpret_cast<const float4*>(Wv)[threadIdx.x];
    const float4 w1 = reinterpret_cast<const float4*>(Wv)[32 + threadIdx.x];
    float4 wd; wd.x = w0.x - w1.x; wd.y = w0.y - w1.y;
    wd.z = w0.z - w1.z; wd.w = w0.w - w1.w;
    wdL[threadIdx.x] = wd;
  }
  __syncthreads();

  const int jj = threadIdx.x & 31;   // j cols: j0+jj, j0+jj+32
  const int ib = threadIdx.x >> 5;   // i rows: ib, ib+8

  // mask prefetch
  const uint32_t row0 = (uint32_t)b * LLEN + i0 + ib;
  const uint32_t col0 = j0 + jj;
  const uint32_t idx00 = row0 * LLEN + col0;
  const uint32_t idx01 = idx00 + 32u;
  const uint32_t idx10 = idx00 + 8u * LLEN;
  const uint32_t idx11 = idx10 + 32u;
  const int m00 = mask[idx00], m01 = mask[idx01];
  const int m10 = mask[idx10], m11 = mask[idx11];

  // Swd = sum_h wd_h (broadcast reads, once)
  float Swd = 0.f;
  #pragma unroll
  for (int t = 0; t < 32; ++t) {
    const float4 wd = wdL[t];
    Swd += (wd.x + wd.y) + (wd.z + wd.w);
  }

  float acc00 = 0.f, acc01 = 0.f, acc10 = 0.f, acc11 = 0.f;

  #pragma unroll 4
  for (int h4 = 0; h4 < HH / 4; ++h4) {
    const float4 kv0 = KL[jj][h4];
    const float4 kv1 = KL[jj + 32][h4];
    const float4 qv0 = QL[ib][h4];
    const float4 qv1 = QL[ib + 8][h4];
    const float4 wd  = wdL[h4];
    GRP(acc00, qv0, kv0, wd)
    GRP(acc01, qv0, kv1, wd)
    GRP(acc10, qv1, kv0, wd)
    GRP(acc11, qv1, kv1, wd)
  }

  // epilogue: out = sigmoid(100*(d + g0 - g1)); g0-g1 = ln(l1/l0), l=log2(u)
  // exp2 arg = 100*log2e*d + 100*log2(l1/l0)
  #define EPI(accv, mreg, idx) {                                        \
      float o_ = 1.0f;                                                  \
      if ((mreg) >= 2) {                                                \
        const float d_  = fmaf(-2.0f, (accv), Swd);                     \
        const float l0_ = __log2f(jax_u01((idx) * 2u));                 \
        const float l1_ = __log2f(jax_u01((idx) * 2u + 1u));            \
        const float rl_ = l1_ * __builtin_amdgcn_rcpf(l0_);             \
        const float dl_ = __log2f(rl_);                                 \
        const float t_  = fmaf(d_, LOG2E_100, 100.0f * dl_);            \
        o_ = __builtin_amdgcn_rcpf(1.0f + __builtin_amdgcn_exp2f(-t_)); \
      }                                                                 \
      out[idx] = o_; }

  EPI(acc00, m00, idx00)
  EPI(acc01, m01, idx01)
  EPI(acc10, m10, idx10)
  EPI(acc11, m11, idx11)
  #undef EPI
}

extern "C" void kernel_launch(void* const* d_in, const int* in_sizes, int n_in,
                              void* d_out, int out_size, void* d_ws, size_t ws_size,
                              hipStream_t stream) {
  const float* queries = (const float*)d_in[0];
  const float* keys    = (const float*)d_in[1];
  const int*   mask    = (const int*)d_in[2];
  const float* Wq      = (const float*)d_in[3];
  const float* Wk      = (const float*)d_in[4];
  const float* Wv      = (const float*)d_in[5];
  float* out = (float*)d_out;

  float* EQ = (float*)d_ws;                 // [2048][128]
  float* EK = EQ + (size_t)BB * LLEN * HH;  // [2048][128]

  proj_kernel<<<dim3(1024), dim3(128), 0, stream>>>(
      queries, keys, Wq, Wk, EQ, EK);
  attn_kernel<<<dim3(LLEN / 16, LLEN / 64, BB), dim3(256), 0, stream>>>(
      EQ, EK, mask, Wv, out);
}